// Round 9
// baseline (171.836 us; speedup 1.0000x reference)
//
#include <hip/hip_runtime.h>

typedef __attribute__((ext_vector_type(8))) __bf16 bf16x8;
typedef __attribute__((ext_vector_type(4))) __bf16 bf16x4;
typedef __attribute__((ext_vector_type(4))) float  f32x4;
typedef __attribute__((ext_vector_type(4))) float  float4v;

#define DEV static __device__ __forceinline__

DEV void gload_lds16(const void* g, void* l) {
  __builtin_amdgcn_global_load_lds(
      (const __attribute__((address_space(1))) void*)g,
      (__attribute__((address_space(3))) void*)l, 16, 0, 0);
}

// ---- merged prep: q cvt | W1 perm-cvt | W2 cvt | softmax(conv_w)+b1 perm ----
__global__ void prep_all_kernel(const float* __restrict__ q, const float* __restrict__ W1,
                                const float* __restrict__ W2, const float* __restrict__ cw,
                                const float* __restrict__ b1,
                                __bf16* __restrict__ qb, __bf16* __restrict__ w1p,
                                __bf16* __restrict__ w2b,
                                float* __restrict__ swm, float* __restrict__ b1p) {
  const int blk = blockIdx.x;
  const int tid = threadIdx.x;
  if (blk < 2048) {
    int i = blk * 256 + tid;
#pragma unroll 8
    for (int it = 0; it < 8; ++it, i += 524288) {
      float4v v = ((const float4v*)q)[i];
      bf16x4 o;
#pragma unroll
      for (int j = 0; j < 4; ++j) o[j] = (__bf16)v[j];
      ((bf16x4*)qb)[i] = o;
    }
  } else if (blk < 3072) {
    const int r   = (blk - 2048) * 2 + (tid >> 7);
    const int col = (tid & 127) * 8;
    const int g  = r >> 8, p = r & 255;
    const int wn = p >> 6, jj = (p >> 4) & 3, c16 = p & 15;
    const int ch = g * 128 + wn * 32 + (jj & 1) * 16 + c16;
    const int src = ch + (jj >= 2 ? 1024 : 0);
    const float* ptr = W1 + (long)src * 1024 + col;
    float4v v0 = *(const float4v*)ptr;
    float4v v1 = *(const float4v*)(ptr + 4);
    bf16x8 o;
#pragma unroll
    for (int j = 0; j < 4; ++j) { o[j] = (__bf16)v0[j]; o[4 + j] = (__bf16)v1[j]; }
    *(bf16x8*)(w1p + (long)r * 1024 + col) = o;
  } else if (blk < 3328) {
    int i = (blk - 3072) * 256 + tid;
#pragma unroll 4
    for (int it = 0; it < 4; ++it, i += 65536) {
      float4v v = ((const float4v*)W2)[i];
      bf16x4 o;
#pragma unroll
      for (int j = 0; j < 4; ++j) o[j] = (__bf16)v[j];
      ((bf16x4*)w2b)[i] = o;
    }
  } else {
    if (tid < 4) {
      const int h = tid;
      float m = cw[h * 31];
#pragma unroll
      for (int k = 1; k < 31; ++k) m = fmaxf(m, cw[h * 31 + k]);
      float e[31];
      float s = 0.f;
#pragma unroll
      for (int k = 0; k < 31; ++k) {
        e[k] = __expf(cw[h * 31 + k] - m);
        s += e[k];
      }
      float inv = 1.f / s;
#pragma unroll
      for (int k = 0; k < 31; ++k) swm[h * 31 + k] = e[k] * inv;
    }
    for (int i = tid; i < 2048; i += 256) {
      const int g = i >> 8, p = i & 255;
      const int wn = p >> 6, jj = (p >> 4) & 3, c16 = p & 15;
      const int ch = g * 128 + wn * 32 + (jj & 1) * 16 + c16;
      b1p[i] = b1[ch + (jj >= 2 ? 1024 : 0)];
    }
  }
}

// ====== 256x256 GEMM, 4 phases/tile, 3-slot rotating A prefetch, no drain ======
// (R8 main loop, unchanged.) MODE 0: f32 out via LDS-packed dwordx4 stores.
// MODE 1: same-lane GLU epilogue, bf16 packed stores.
template <int MODE>
DEV void gemm_body(const __bf16* __restrict__ A, const __bf16* __restrict__ Bw,
                   const float* __restrict__ bias, void* __restrict__ Cout,
                   int M, int N, int K, int ntn) {
  __shared__ __align__(16) __bf16 Al[3 * 16384];  // 96KB
  __shared__ __align__(16) __bf16 Bl[2 * 16384];  // 64KB

  const int tid  = threadIdx.x;
  const int lane = tid & 63;
  const int w    = tid >> 6;
  const int wm = w >> 2, wn = w & 3;

  const int nwg = gridDim.x;
  const int cpx = nwg >> 3;
  const int bid = blockIdx.x;
  const int wgid = (bid & 7) * cpx + (bid >> 3);
  const int m0 = (wgid / ntn) * 256;
  const int n0 = (wgid % ntn) * 256;

  const int NT = K >> 6;

  const int scolE = ((((tid & 7) * 16) ^ (((tid >> 3) & 7) << 4)) >> 1);
  const __bf16* __restrict__ Abase = A + (long)m0 * K;
  const __bf16* __restrict__ Bbase = Bw + (long)n0 * K;

  const int l15 = lane & 15;
  const int xk  = (l15 & 7) << 4;
  const int a0  = l15 * 128 + (((lane >> 4) * 16) ^ xk);
  const int a1  = l15 * 128 + ((((lane >> 4) * 16) + 64) ^ xk);
  const int bq  = (wn & 1) * 8192;
  const int b0  = bq + a0;
  const int b1r = bq + a1;

  f32x4 acc[8][4];
#pragma unroll
  for (int i = 0; i < 8; ++i)
#pragma unroll
    for (int j = 0; j < 4; ++j) {
      acc[i][j][0] = 0.f; acc[i][j][1] = 0.f;
      acc[i][j][2] = 0.f; acc[i][j][3] = 0.f;
    }
  bf16x8 af[8], bf[8];

#define STAGEG(base, groff, ktc, dst)                                             \
  {                                                                               \
    const __bf16* _s = (base) + (long)((groff) + (tid >> 3)) * K + (ktc) + scolE; \
    gload_lds16(_s, (dst) + tid * 8);                                             \
    gload_lds16(_s + (long)64 * K, (dst) + 4096 + tid * 8);                       \
  }

#define PH_MID()                                     \
  __builtin_amdgcn_s_barrier();                      \
  asm volatile("s_waitcnt lgkmcnt(0)" ::: "memory"); \
  __builtin_amdgcn_s_setprio(1);

#define PH_ENDN()                                    \
  __builtin_amdgcn_s_setprio(0);                     \
  __builtin_amdgcn_s_barrier();

#define PH_END4()                                    \
  __builtin_amdgcn_s_setprio(0);                     \
  asm volatile("s_waitcnt vmcnt(4)" ::: "memory");   \
  __builtin_amdgcn_s_barrier();

#define RDA(IB, G)                                                    \
  _Pragma("unroll") for (int i2 = 0; i2 < 4; ++i2) {                  \
    af[i2 * 2 + 0] = *(const bf16x8*)((G) + ((IB) + i2) * 2048 + a0); \
    af[i2 * 2 + 1] = *(const bf16x8*)((G) + ((IB) + i2) * 2048 + a1); \
  }
#define RDB(JB, G)                                                                \
  _Pragma("unroll") for (int j2 = 0; j2 < 2; ++j2) {                              \
    bf[(JB) * 2 + j2 * 2 + 0] = *(const bf16x8*)((G) + ((JB) + j2) * 2048 + b0);  \
    bf[(JB) * 2 + j2 * 2 + 1] = *(const bf16x8*)((G) + ((JB) + j2) * 2048 + b1r); \
  }

#define MMQ(IB, JB)                                                           \
  _Pragma("unroll") for (int i2 = 0; i2 < 4; ++i2)                            \
  _Pragma("unroll") for (int j2 = 0; j2 < 2; ++j2)                            \
  _Pragma("unroll") for (int kk = 0; kk < 2; ++kk)                            \
      acc[(IB) + i2][(JB) + j2] = __builtin_amdgcn_mfma_f32_16x16x32_bf16(    \
          af[i2 * 2 + kk], bf[(JB) * 2 + j2 * 2 + kk], acc[(IB) + i2][(JB) + j2], 0, 0, 0);

  __bf16* aRd = Al;
  __bf16* aNx = Al + 16384;
  __bf16* aSt = Al + 32768;
  __bf16* bRd = Bl;
  __bf16* bSt = Bl + 16384;

  STAGEG(Abase, 0,   0, aRd);
  STAGEG(Abase, 128, 0, aRd + 8192);
  STAGEG(Bbase, 0,   0, bRd);
  STAGEG(Bbase, 128, 0, bRd + 8192);
  {
    const int k1 = (1 < NT ? 1 : NT - 1) * 64;
    STAGEG(Abase, 0,   k1, aNx);
    STAGEG(Abase, 128, k1, aNx + 8192);
  }
  asm volatile("s_waitcnt vmcnt(4)" ::: "memory");
  __builtin_amdgcn_s_barrier();

#pragma unroll 1
  for (int t = 0; t < NT; ++t) {
    const int kB = ((t + 1 < NT) ? t + 1 : NT - 1) * 64;
    const int kA = ((t + 2 < NT) ? t + 2 : NT - 1) * 64;
    const char* aG = (const char*)aRd + wm * 16384;
    const char* bG = (const char*)bRd + (wn >> 1) * 16384;
    RDA(0, aG); RDB(0, bG);
    STAGEG(Bbase, 0,   kB, bSt);
    STAGEG(Bbase, 128, kB, bSt + 8192);
    PH_MID(); MMQ(0, 0); PH_ENDN();
    RDB(2, bG);
    STAGEG(Abase, 0,   kA, aSt);
    STAGEG(Abase, 128, kA, aSt + 8192);
    PH_MID(); MMQ(0, 2); PH_ENDN();
    RDA(4, aG);
    PH_MID(); MMQ(4, 0); PH_ENDN();
    PH_MID(); MMQ(4, 2); PH_END4();
    __bf16* ta = aRd; aRd = aNx; aNx = aSt; aSt = ta;
    __bf16* tb = bRd; bRd = bSt; bSt = tb;
  }

  asm volatile("s_waitcnt vmcnt(0)" ::: "memory");

  // ---- epilogue: C/D layout col=lane&15, row=(lane>>4)*4+reg ----
  const int crow = (lane >> 4) * 4;
  const int ccol = lane & 15;
  if (MODE == 0) {
    // packed f32 stores via per-wave LDS transpose: 16 rows x (64+4 pad) f32
    __builtin_amdgcn_s_barrier();
    float* wa = (float*)Al + w * 1088;
    const int rr = lane >> 2, cs = (lane & 3) * 16;
#pragma unroll
    for (int i = 0; i < 8; ++i) {
#pragma unroll
      for (int j = 0; j < 4; ++j) {
        const int ncol = n0 + wn * 64 + j * 16 + ccol;
        const float bv = bias[ncol];
#pragma unroll
        for (int r = 0; r < 4; ++r)
          wa[(crow + r) * 68 + j * 16 + ccol] = acc[i][j][r] + bv;
      }
      const int gr = m0 + wm * 128 + i * 16 + rr;
      float* dst = (float*)Cout + (long)gr * N + n0 + wn * 64 + cs;
#pragma unroll
      for (int s = 0; s < 4; ++s)
        *(float4v*)(dst + s * 4) = *(const f32x4*)(wa + rr * 68 + cs + s * 4);
    }
  } else {
    // GLU same-lane + per-wave LDS transpose to pack stores as bf16x8.
    __builtin_amdgcn_s_barrier();
    __bf16* wa = (__bf16*)Al + w * 640;
    const int chbase = (n0 >> 1) + wn * 32;
    const int rr = lane >> 2, c8 = (lane & 3) * 8;
#pragma unroll
    for (int i = 0; i < 8; ++i) {
#pragma unroll
      for (int j = 0; j < 2; ++j) {
        const int na = n0 + wn * 64 + j * 16 + ccol;
        const float bva = bias[na];
        const float bvg = bias[na + 32];
#pragma unroll
        for (int r = 0; r < 4; ++r) {
          float a = acc[i][j][r] + bva;
          float gv = acc[i][j + 2][r] + bvg;
          float res = a * __builtin_amdgcn_rcpf(1.f + __expf(-gv));
          wa[(crow + r) * 40 + j * 16 + ccol] = (__bf16)res;
        }
      }
      bf16x8 v = *(const bf16x8*)(wa + rr * 40 + c8);
      const int gr = m0 + wm * 128 + i * 16 + rr;
      *(bf16x8*)((__bf16*)Cout + (long)gr * (N >> 1) + chbase + c8) = v;
    }
  }
#undef STAGEG
#undef PH_MID
#undef PH_ENDN
#undef PH_END4
#undef RDA
#undef RDB
#undef MMQ
}

__global__ __launch_bounds__(512, 1)
void gemm1_glu_kernel(const __bf16* __restrict__ A, const __bf16* __restrict__ Bw,
                      const float* __restrict__ bias, void* __restrict__ Cout,
                      int M, int N, int K, int ntn) {
  gemm_body<1>(A, Bw, bias, Cout, M, N, K, ntn);
}

__global__ __launch_bounds__(512, 1)
void gemm2_out_kernel(const __bf16* __restrict__ A, const __bf16* __restrict__ Bw,
                      const float* __restrict__ bias, void* __restrict__ Cout,
                      int M, int N, int K, int ntn) {
  gemm_body<0>(A, Bw, bias, Cout, M, N, K, ntn);
}

// ------- depthwise conv (K=31, pad 15) + bias + mask (input already GLU'd) ----
// Loader restructured: thread owns 4 taps x 8 ch; in-register transpose;
// 8 x ds_write_b128 (conflict-free: tq%8 = lane&7 spans all 8 keys).
__global__ __launch_bounds__(256, 2)
void conv_kernel(const __bf16* __restrict__ Yin, const float* __restrict__ Wsm,
                 const float* __restrict__ bias, const int* __restrict__ mask,
                 __bf16* __restrict__ Y) {
  const int b  = blockIdx.z;
  const int t0 = blockIdx.y * 64;
  const int c0 = blockIdx.x * 128;
  __shared__ float sgT[128][128];
  __shared__ float swl[124];
  const int tid = threadIdx.x;
  if (tid < 124) swl[tid] = Wsm[tid];

  // tap-quad loader: tql = wave*8 + (lane&7) in 0..31 (only <24 used),
  // cg = (lane>>3)&7 (+8 on second half). Taps 94..95 zero-filled.
  const int tql = (tid >> 6) * 8 + (tid & 7);
  const int cg0 = (tid >> 3) & 7;
  if (tql < 24) {
#pragma unroll
    for (int half = 0; half < 2; ++half) {
      const int cg = cg0 + half * 8;
      float v[4][8];
#pragma unroll
      for (int s = 0; s < 4; ++s) {
        const int tap = tql * 4 + s;
        const int t = t0 - 15 + tap;
        if (tap < 94 && t >= 0 && t < 1024) {
          bf16x8 a8 = *(const bf16x8*)(Yin + ((long)(b * 1024 + t)) * 1024 + c0 + cg * 8);
#pragma unroll
          for (int j = 0; j < 8; ++j) v[s][j] = (float)a8[j];
        } else {
#pragma unroll
          for (int j = 0; j < 8; ++j) v[s][j] = 0.f;
        }
      }
#pragma unroll
      for (int j = 0; j < 8; ++j) {
        f32x4 wv = {v[0][j], v[1][j], v[2][j], v[3][j]};
        *(f32x4*)&sgT[cg * 8 + j][(tql ^ (j << 2)) << 2] = wv;
      }
    }
  }
  __syncthreads();

  const int cc = tid & 127;
  const int th = tid >> 7;
  const int c  = c0 + cc;
  const float* wrow = swl + (c & 3) * 31;
  const float bv = bias[c];
  float acc[32];
#pragma unroll
  for (int u = 0; u < 32; ++u) acc[u] = bv;
  const int key = (cc & 7) << 2;
#pragma unroll
  for (int qi = 0; qi < 16; ++qi) {
    const int q = th * 8 + qi;
    const f32x4 w4 = *(const f32x4*)&sgT[cc][(q ^ key) << 2];
#pragma unroll
    for (int j = 0; j < 4; ++j) {
      const int rl = qi * 4 + j;
#pragma unroll
      for (int u = 0; u < 32; ++u) {
        const int k = rl - u;
        if (k >= 0 && k < 31) acc[u] += w4[j] * wrow[k];
      }
    }
  }
  const long yb = (long)b * 1024 * 1024;
#pragma unroll
  for (int u = 0; u < 32; ++u) {
    const int gt = t0 + th * 32 + u;
    float v = acc[u];
    if (mask[b * 1024 + gt] == 0) v = 0.f;
    Y[yb + (long)gt * 1024 + c] = (__bf16)v;
  }
}

extern "C" void kernel_launch(void* const* d_in, const int* in_sizes, int n_in,
                              void* d_out, int out_size, void* d_ws, size_t ws_size,
                              hipStream_t stream) {
  const float* q    = (const float*)d_in[0];
  const int*   mask = (const int*)d_in[3];
  const float* W1   = (const float*)d_in[4];
  const float* b1   = (const float*)d_in[5];
  const float* W2   = (const float*)d_in[6];
  const float* b2   = (const float*)d_in[7];
  const float* cw   = (const float*)d_in[8];
  const float* bias = (const float*)d_in[9];

  char* ws = (char*)d_ws;
  __bf16* q_bf  = (__bf16*)(ws);                // 32 MB; dead after GEMM1 -> reused as yc
  __bf16* w1p   = (__bf16*)(ws + (32u << 20));  // 4 MB (permuted)
  __bf16* w2_bf = (__bf16*)(ws + (36u << 20));  // 2 MB
  float*  swm   = (float*)(ws + (38u << 20));   // 496 B
  float*  b1p   = (float*)(ws + (38u << 20) + 4096);  // 8 KB (permuted)
  __bf16* y     = (__bf16*)d_out;               // (B,T,C) bf16 = 32 MB; dead after conv
  __bf16* yc    = q_bf;                         // conv output over dead q_bf

  prep_all_kernel<<<3329, 256, 0, stream>>>(q, W1, W2, cw, b1,
                                            q_bf, w1p, w2_bf, swm, b1p);

  // GEMM1 (+b1, GLU fused) -> y bf16 (B,T,C) in d_out. grid 64x8=512.
  gemm1_glu_kernel<<<512, 512, 0, stream>>>(q_bf, w1p, b1p, (void*)y,
                                            16384, 2048, 1024, 8);
  // depthwise conv + bias + mask: y -> yc
  conv_kernel<<<dim3(8, 16, 16), 256, 0, stream>>>(y, swm, bias, mask, yc);
  // GEMM2 + b2 -> d_out f32. grid 64x4=256.
  gemm2_out_kernel<<<256, 512, 0, stream>>>(yc, w2_bf, b2, d_out,
                                            16384, 1024, 1024, 4);
}

// Round 10
// 156.973 us; speedup vs baseline: 1.0947x; 1.0947x over previous
//
#include <hip/hip_runtime.h>

typedef __attribute__((ext_vector_type(8))) __bf16 bf16x8;
typedef __attribute__((ext_vector_type(4))) __bf16 bf16x4;
typedef __attribute__((ext_vector_type(4))) float  f32x4;
typedef __attribute__((ext_vector_type(4))) float  float4v;

#define DEV static __device__ __forceinline__

DEV void gload_lds16(const void* g, void* l) {
  __builtin_amdgcn_global_load_lds(
      (const __attribute__((address_space(1))) void*)g,
      (__attribute__((address_space(3))) void*)l, 16, 0, 0);
}

// ---- merged prep: q cvt | W1 perm-cvt | W2 cvt | softmax(conv_w)+b1 perm ----
__global__ void prep_all_kernel(const float* __restrict__ q, const float* __restrict__ W1,
                                const float* __restrict__ W2, const float* __restrict__ cw,
                                const float* __restrict__ b1,
                                __bf16* __restrict__ qb, __bf16* __restrict__ w1p,
                                __bf16* __restrict__ w2b,
                                float* __restrict__ swm, float* __restrict__ b1p) {
  const int blk = blockIdx.x;
  const int tid = threadIdx.x;
  if (blk < 2048) {
    int i = blk * 256 + tid;
#pragma unroll 8
    for (int it = 0; it < 8; ++it, i += 524288) {
      float4v v = ((const float4v*)q)[i];
      bf16x4 o;
#pragma unroll
      for (int j = 0; j < 4; ++j) o[j] = (__bf16)v[j];
      ((bf16x4*)qb)[i] = o;
    }
  } else if (blk < 3072) {
    const int r   = (blk - 2048) * 2 + (tid >> 7);
    const int col = (tid & 127) * 8;
    const int g  = r >> 8, p = r & 255;
    const int wn = p >> 6, jj = (p >> 4) & 3, c16 = p & 15;
    const int ch = g * 128 + wn * 32 + (jj & 1) * 16 + c16;
    const int src = ch + (jj >= 2 ? 1024 : 0);
    const float* ptr = W1 + (long)src * 1024 + col;
    float4v v0 = *(const float4v*)ptr;
    float4v v1 = *(const float4v*)(ptr + 4);
    bf16x8 o;
#pragma unroll
    for (int j = 0; j < 4; ++j) { o[j] = (__bf16)v0[j]; o[4 + j] = (__bf16)v1[j]; }
    *(bf16x8*)(w1p + (long)r * 1024 + col) = o;
  } else if (blk < 3328) {
    int i = (blk - 3072) * 256 + tid;
#pragma unroll 4
    for (int it = 0; it < 4; ++it, i += 65536) {
      float4v v = ((const float4v*)W2)[i];
      bf16x4 o;
#pragma unroll
      for (int j = 0; j < 4; ++j) o[j] = (__bf16)v[j];
      ((bf16x4*)w2b)[i] = o;
    }
  } else {
    if (tid < 4) {
      const int h = tid;
      float m = cw[h * 31];
#pragma unroll
      for (int k = 1; k < 31; ++k) m = fmaxf(m, cw[h * 31 + k]);
      float e[31];
      float s = 0.f;
#pragma unroll
      for (int k = 0; k < 31; ++k) {
        e[k] = __expf(cw[h * 31 + k] - m);
        s += e[k];
      }
      float inv = 1.f / s;
#pragma unroll
      for (int k = 0; k < 31; ++k) swm[h * 31 + k] = e[k] * inv;
    }
    for (int i = tid; i < 2048; i += 256) {
      const int g = i >> 8, p = i & 255;
      const int wn = p >> 6, jj = (p >> 4) & 3, c16 = p & 15;
      const int ch = g * 128 + wn * 32 + (jj & 1) * 16 + c16;
      b1p[i] = b1[ch + (jj >= 2 ? 1024 : 0)];
    }
  }
}

// ====== 256x256 GEMM, 4 phases/tile, 3-slot rotating A prefetch, no drain ======
// (R8 main loop.) MODE 0: f32 out, LDS-transposed row-contiguous dwordx4 stores.
// MODE 1: same-lane GLU epilogue, bf16 packed stores.
template <int MODE>
DEV void gemm_body(const __bf16* __restrict__ A, const __bf16* __restrict__ Bw,
                   const float* __restrict__ bias, void* __restrict__ Cout,
                   int M, int N, int K, int ntn) {
  __shared__ __align__(16) __bf16 Al[3 * 16384];  // 96KB
  __shared__ __align__(16) __bf16 Bl[2 * 16384];  // 64KB

  const int tid  = threadIdx.x;
  const int lane = tid & 63;
  const int w    = tid >> 6;
  const int wm = w >> 2, wn = w & 3;

  const int nwg = gridDim.x;
  const int cpx = nwg >> 3;
  const int bid = blockIdx.x;
  const int wgid = (bid & 7) * cpx + (bid >> 3);
  const int m0 = (wgid / ntn) * 256;
  const int n0 = (wgid % ntn) * 256;

  const int NT = K >> 6;

  const int scolE = ((((tid & 7) * 16) ^ (((tid >> 3) & 7) << 4)) >> 1);
  const __bf16* __restrict__ Abase = A + (long)m0 * K;
  const __bf16* __restrict__ Bbase = Bw + (long)n0 * K;

  const int l15 = lane & 15;
  const int xk  = (l15 & 7) << 4;
  const int a0  = l15 * 128 + (((lane >> 4) * 16) ^ xk);
  const int a1  = l15 * 128 + ((((lane >> 4) * 16) + 64) ^ xk);
  const int bq  = (wn & 1) * 8192;
  const int b0  = bq + a0;
  const int b1r = bq + a1;

  f32x4 acc[8][4];
#pragma unroll
  for (int i = 0; i < 8; ++i)
#pragma unroll
    for (int j = 0; j < 4; ++j) {
      acc[i][j][0] = 0.f; acc[i][j][1] = 0.f;
      acc[i][j][2] = 0.f; acc[i][j][3] = 0.f;
    }
  bf16x8 af[8], bf[8];

#define STAGEG(base, groff, ktc, dst)                                             \
  {                                                                               \
    const __bf16* _s = (base) + (long)((groff) + (tid >> 3)) * K + (ktc) + scolE; \
    gload_lds16(_s, (dst) + tid * 8);                                             \
    gload_lds16(_s + (long)64 * K, (dst) + 4096 + tid * 8);                       \
  }

#define PH_MID()                                     \
  __builtin_amdgcn_s_barrier();                      \
  asm volatile("s_waitcnt lgkmcnt(0)" ::: "memory"); \
  __builtin_amdgcn_s_setprio(1);

#define PH_ENDN()                                    \
  __builtin_amdgcn_s_setprio(0);                     \
  __builtin_amdgcn_s_barrier();

#define PH_END4()                                    \
  __builtin_amdgcn_s_setprio(0);                     \
  asm volatile("s_waitcnt vmcnt(4)" ::: "memory");   \
  __builtin_amdgcn_s_barrier();

#define RDA(IB, G)                                                    \
  _Pragma("unroll") for (int i2 = 0; i2 < 4; ++i2) {                  \
    af[i2 * 2 + 0] = *(const bf16x8*)((G) + ((IB) + i2) * 2048 + a0); \
    af[i2 * 2 + 1] = *(const bf16x8*)((G) + ((IB) + i2) * 2048 + a1); \
  }
#define RDB(JB, G)                                                                \
  _Pragma("unroll") for (int j2 = 0; j2 < 2; ++j2) {                              \
    bf[(JB) * 2 + j2 * 2 + 0] = *(const bf16x8*)((G) + ((JB) + j2) * 2048 + b0);  \
    bf[(JB) * 2 + j2 * 2 + 1] = *(const bf16x8*)((G) + ((JB) + j2) * 2048 + b1r); \
  }

#define MMQ(IB, JB)                                                           \
  _Pragma("unroll") for (int i2 = 0; i2 < 4; ++i2)                            \
  _Pragma("unroll") for (int j2 = 0; j2 < 2; ++j2)                            \
  _Pragma("unroll") for (int kk = 0; kk < 2; ++kk)                            \
      acc[(IB) + i2][(JB) + j2] = __builtin_amdgcn_mfma_f32_16x16x32_bf16(    \
          af[i2 * 2 + kk], bf[(JB) * 2 + j2 * 2 + kk], acc[(IB) + i2][(JB) + j2], 0, 0, 0);

  __bf16* aRd = Al;
  __bf16* aNx = Al + 16384;
  __bf16* aSt = Al + 32768;
  __bf16* bRd = Bl;
  __bf16* bSt = Bl + 16384;

  STAGEG(Abase, 0,   0, aRd);
  STAGEG(Abase, 128, 0, aRd + 8192);
  STAGEG(Bbase, 0,   0, bRd);
  STAGEG(Bbase, 128, 0, bRd + 8192);
  {
    const int k1 = (1 < NT ? 1 : NT - 1) * 64;
    STAGEG(Abase, 0,   k1, aNx);
    STAGEG(Abase, 128, k1, aNx + 8192);
  }
  asm volatile("s_waitcnt vmcnt(4)" ::: "memory");
  __builtin_amdgcn_s_barrier();

#pragma unroll 1
  for (int t = 0; t < NT; ++t) {
    const int kB = ((t + 1 < NT) ? t + 1 : NT - 1) * 64;
    const int kA = ((t + 2 < NT) ? t + 2 : NT - 1) * 64;
    const char* aG = (const char*)aRd + wm * 16384;
    const char* bG = (const char*)bRd + (wn >> 1) * 16384;
    RDA(0, aG); RDB(0, bG);
    STAGEG(Bbase, 0,   kB, bSt);
    STAGEG(Bbase, 128, kB, bSt + 8192);
    PH_MID(); MMQ(0, 0); PH_ENDN();
    RDB(2, bG);
    STAGEG(Abase, 0,   kA, aSt);
    STAGEG(Abase, 128, kA, aSt + 8192);
    PH_MID(); MMQ(0, 2); PH_ENDN();
    RDA(4, aG);
    PH_MID(); MMQ(4, 0); PH_ENDN();
    PH_MID(); MMQ(4, 2); PH_END4();
    __bf16* ta = aRd; aRd = aNx; aNx = aSt; aSt = ta;
    __bf16* tb = bRd; bRd = bSt; bSt = tb;
  }

  asm volatile("s_waitcnt vmcnt(0)" ::: "memory");

  // ---- epilogue: C/D layout col=lane&15, row=(lane>>4)*4+reg ----
  const int crow = (lane >> 4) * 4;
  const int ccol = lane & 15;
  if (MODE == 0) {
    // per-wave LDS transpose; stores are full 256B rows (16 lanes x 16B), 4 rows/instr
    __builtin_amdgcn_s_barrier();
    float* wa = (float*)Al + w * 1088;  // 16 rows x 68 f32 (pad 4)
    const int rr = lane >> 4;           // 0..3
    const int cf = (lane & 15) * 4;     // 0..60, 16 lanes cover a whole row
#pragma unroll
    for (int i = 0; i < 8; ++i) {
#pragma unroll
      for (int j = 0; j < 4; ++j) {
        const int ncol = n0 + wn * 64 + j * 16 + ccol;
        const float bv = bias[ncol];
#pragma unroll
        for (int r = 0; r < 4; ++r)
          wa[(crow + r) * 68 + j * 16 + ccol] = acc[i][j][r] + bv;
      }
#pragma unroll
      for (int s = 0; s < 4; ++s) {
        const int row = s * 4 + rr;
        const int gr = m0 + wm * 128 + i * 16 + row;
        *(float4v*)((float*)Cout + (long)gr * N + n0 + wn * 64 + cf) =
            *(const f32x4*)(wa + row * 68 + cf);
      }
    }
  } else {
    // GLU same-lane + per-wave LDS transpose to pack stores as bf16x8.
    __builtin_amdgcn_s_barrier();
    __bf16* wa = (__bf16*)Al + w * 640;
    const int chbase = (n0 >> 1) + wn * 32;
    const int rr = lane >> 2, c8 = (lane & 3) * 8;
#pragma unroll
    for (int i = 0; i < 8; ++i) {
#pragma unroll
      for (int j = 0; j < 2; ++j) {
        const int na = n0 + wn * 64 + j * 16 + ccol;
        const float bva = bias[na];
        const float bvg = bias[na + 32];
#pragma unroll
        for (int r = 0; r < 4; ++r) {
          float a = acc[i][j][r] + bva;
          float gv = acc[i][j + 2][r] + bvg;
          float res = a * __builtin_amdgcn_rcpf(1.f + __expf(-gv));
          wa[(crow + r) * 40 + j * 16 + ccol] = (__bf16)res;
        }
      }
      bf16x8 v = *(const bf16x8*)(wa + rr * 40 + c8);
      const int gr = m0 + wm * 128 + i * 16 + rr;
      *(bf16x8*)((__bf16*)Cout + (long)gr * (N >> 1) + chbase + c8) = v;
    }
  }
#undef STAGEG
#undef PH_MID
#undef PH_ENDN
#undef PH_END4
#undef RDA
#undef RDB
#undef MMQ
}

__global__ __launch_bounds__(512, 1)
void gemm1_glu_kernel(const __bf16* __restrict__ A, const __bf16* __restrict__ Bw,
                      const float* __restrict__ bias, void* __restrict__ Cout,
                      int M, int N, int K, int ntn) {
  gemm_body<1>(A, Bw, bias, Cout, M, N, K, ntn);
}

__global__ __launch_bounds__(512, 1)
void gemm2_out_kernel(const __bf16* __restrict__ A, const __bf16* __restrict__ Bw,
                      const float* __restrict__ bias, void* __restrict__ Cout,
                      int M, int N, int K, int ntn) {
  gemm_body<0>(A, Bw, bias, Cout, M, N, K, ntn);
}

// ------- depthwise conv (K=31, pad 15) + bias + mask (R8 loader, proven) ----
__global__ __launch_bounds__(256, 2)
void conv_kernel(const __bf16* __restrict__ Yin, const float* __restrict__ Wsm,
                 const float* __restrict__ bias, const int* __restrict__ mask,
                 __bf16* __restrict__ Y) {
  const int b  = blockIdx.z;
  const int t0 = blockIdx.y * 64;
  const int c0 = blockIdx.x * 128;
  __shared__ float sgT[128][128];
  __shared__ float swl[124];
  const int tid = threadIdx.x;
  if (tid < 124) swl[tid] = Wsm[tid];

  for (int i = tid; i < 2048; i += 256) {
    const int ttl = i & 127;  // tap 0..127 (94 used)
    const int cg  = i >> 7;   // channel octet 0..15
    if (ttl < 94) {
      const int t = t0 - 15 + ttl;
      float v[8];
      if (t >= 0 && t < 1024) {
        bf16x8 a8 = *(const bf16x8*)(Yin + ((long)(b * 1024 + t)) * 1024 + c0 + cg * 8);
#pragma unroll
        for (int j = 0; j < 8; ++j) v[j] = (float)a8[j];
      } else {
#pragma unroll
        for (int j = 0; j < 8; ++j) v[j] = 0.f;
      }
      const int q = ttl >> 2, e = ttl & 3;
#pragma unroll
      for (int j = 0; j < 8; ++j) {
        const int c = cg * 8 + j;
        sgT[c][((q ^ ((c & 7) << 2)) << 2) + e] = v[j];
      }
    }
  }
  __syncthreads();

  const int cc = tid & 127;
  const int th = tid >> 7;
  const int c  = c0 + cc;
  const float* wrow = swl + (c & 3) * 31;
  const float bv = bias[c];
  float acc[32];
#pragma unroll
  for (int u = 0; u < 32; ++u) acc[u] = bv;
  const int key = (cc & 7) << 2;
#pragma unroll
  for (int qi = 0; qi < 16; ++qi) {
    const int q = th * 8 + qi;
    const f32x4 w4 = *(const f32x4*)&sgT[cc][(q ^ key) << 2];
#pragma unroll
    for (int j = 0; j < 4; ++j) {
      const int rl = qi * 4 + j;
#pragma unroll
      for (int u = 0; u < 32; ++u) {
        const int k = rl - u;
        if (k >= 0 && k < 31) acc[u] += w4[j] * wrow[k];
      }
    }
  }
  const long yb = (long)b * 1024 * 1024;
#pragma unroll
  for (int u = 0; u < 32; ++u) {
    const int gt = t0 + th * 32 + u;
    float v = acc[u];
    if (mask[b * 1024 + gt] == 0) v = 0.f;
    Y[yb + (long)gt * 1024 + c] = (__bf16)v;
  }
}

extern "C" void kernel_launch(void* const* d_in, const int* in_sizes, int n_in,
                              void* d_out, int out_size, void* d_ws, size_t ws_size,
                              hipStream_t stream) {
  const float* q    = (const float*)d_in[0];
  const int*   mask = (const int*)d_in[3];
  const float* W1   = (const float*)d_in[4];
  const float* b1   = (const float*)d_in[5];
  const float* W2   = (const float*)d_in[6];
  const float* b2   = (const float*)d_in[7];
  const float* cw   = (const float*)d_in[8];
  const float* bias = (const float*)d_in[9];

  char* ws = (char*)d_ws;
  __bf16* q_bf  = (__bf16*)(ws);                // 32 MB; dead after GEMM1 -> reused as yc
  __bf16* w1p   = (__bf16*)(ws + (32u << 20));  // 4 MB (permuted)
  __bf16* w2_bf = (__bf16*)(ws + (36u << 20));  // 2 MB
  float*  swm   = (float*)(ws + (38u << 20));   // 496 B
  float*  b1p   = (float*)(ws + (38u << 20) + 4096);  // 8 KB (permuted)
  __bf16* y     = (__bf16*)d_out;               // (B,T,C) bf16 = 32 MB; dead after conv
  __bf16* yc    = q_bf;                         // conv output over dead q_bf

  prep_all_kernel<<<3329, 256, 0, stream>>>(q, W1, W2, cw, b1,
                                            q_bf, w1p, w2_bf, swm, b1p);

  // GEMM1 (+b1, GLU fused) -> y bf16 (B,T,C) in d_out. grid 64x8=512.
  gemm1_glu_kernel<<<512, 512, 0, stream>>>(q_bf, w1p, b1p, (void*)y,
                                            16384, 2048, 1024, 8);
  // depthwise conv + bias + mask: y -> yc
  conv_kernel<<<dim3(8, 16, 16), 256, 0, stream>>>(y, swm, bias, mask, yc);
  // GEMM2 + b2 -> d_out f32. grid 64x4=256.
  gemm2_out_kernel<<<256, 512, 0, stream>>>(yc, w2_bf, b2, d_out,
                                            16384, 1024, 1024, 4);
}